// Round 7
// baseline (126.885 us; speedup 1.0000x reference)
//
#include <hip/hip_runtime.h>
#include <hip/hip_bf16.h>

#define NROWS 16384
#define DIM 64
#define BCOLS 256                  // B tile: 256 cols x 64 k = 32 KB, staged ONCE
#define BROWS 1024                 // 8 waves x 2 si x 64 rows
#define NCS (NROWS / BCOLS)        // 64
#define NRG (NROWS / BROWS)        // 16
#define NBLK (NRG * NCS)           // 1024 = exactly 4 blocks/CU = 32 waves/CU

static constexpr float TAU = 0.28f;
static constexpr float EPS = 1e-8f;
static constexpr float EXP2_SCALE = (float)(1.0 / (0.28 * 0.6931471805599453));
static constexpr float LN2F = 0.69314718055994530942f;

using short8 = __attribute__((ext_vector_type(8))) short;
using f32x4  = __attribute__((ext_vector_type(4))) float;

typedef __attribute__((address_space(1))) const unsigned char ga_t;
typedef __attribute__((address_space(3))) unsigned char la_t;

// Kernel 1: per-row L2 normalize; A = bf16(EXP2_SCALE*u_norm),
// W = bf16(u_norm+i_norm), p[n] = dot/TAU; zero total[] and the ticket.
__global__ __launch_bounds__(256) void prep_kernel(
    const float* __restrict__ u, const float* __restrict__ v,
    __hip_bfloat16* __restrict__ a_out, __hip_bfloat16* __restrict__ w_out,
    float* __restrict__ p_out, float* __restrict__ total, int* __restrict__ ticket)
{
    const int lane = threadIdx.x & 63;
    const int wv   = threadIdx.x >> 6;
    const int row  = blockIdx.x * 4 + wv;

    const float uu = u[row * DIM + lane];
    const float ii = v[row * DIM + lane];
    float su = uu * uu, si = ii * ii, sd = uu * ii;
#pragma unroll
    for (int m = 1; m < 64; m <<= 1) {
        su += __shfl_xor(su, m, 64);
        si += __shfl_xor(si, m, 64);
        sd += __shfl_xor(sd, m, 64);
    }
    const float inv_u = 1.0f / fmaxf(sqrtf(su), 1e-12f);
    const float inv_i = 1.0f / fmaxf(sqrtf(si), 1e-12f);
    const float un = uu * inv_u;
    const float in = ii * inv_i;
    a_out[row * DIM + lane] = __float2bfloat16(EXP2_SCALE * un);
    w_out[row * DIM + lane] = __float2bfloat16(un + in);
    if (lane == 0) {
        p_out[row] = sd * inv_u * inv_i * (1.0f / TAU);
        total[row] = 0.0f;
    }
    if (blockIdx.x == 0 && threadIdx.x == 0) ticket[0] = 0;
}

// Kernel 2: fused GEMM + exp + row-sum (+ last-block finalize).
// R4's proven single-stage/one-barrier structure, re-dimensioned for max
// residency: 32 KB tile -> 4 blocks/CU x 8 waves = 32 waves/CU (HW max,
// VGPR<=64 required -- measured 52 for this inner loop in R6). 1024 blocks
// = 16 rg x 64 cs, zero tail. Each wave: 2 si steps of 64 rows (rs=4, so
// each LDS B-pair feeds 8 MFMAs). Only in-loop global traffic: 8 A-frag
// dwordx4 per wave per si.
__global__ __launch_bounds__(512, 4) void score_kernel(
    const __hip_bfloat16* __restrict__ A, const __hip_bfloat16* __restrict__ W,
    float* __restrict__ total, const float* __restrict__ p,
    int* __restrict__ ticket, float* __restrict__ out)
{
    __shared__ alignas(16) ushort blds[BCOLS * DIM];   // 32 KB

    const int tid  = threadIdx.x;
    const int lane = tid & 63;
    const int wv   = tid >> 6;          // 0..7
    const int l15  = lane & 15;
    const int quad = lane >> 4;
    const int cs   = blockIdx.x & (NCS - 1);
    const int rg   = blockIdx.x >> 6;
    const int col0    = cs * BCOLS;
    const int rowbase = rg * BROWS;

    const ushort* Au = (const ushort*)A;
    const ushort* Wu = (const ushort*)W;

    // Stage B ONCE: 2048 16-B chunks, 4/thread; physical slot pp -> LDS
    // pp*16, global k-chunk c = (pp&7) ^ (col&7) (read-side swizzle
    // cancels it; 0 bank conflicts measured R4-R6).
#pragma unroll
    for (int q = 0; q < 4; q++) {
        const int pp = q * 512 + tid;
        const int j  = pp >> 3;
        const int c  = (pp & 7) ^ (j & 7);
        const ushort* g = Wu + (size_t)(col0 + j) * DIM + c * 8;
        __builtin_amdgcn_global_load_lds((ga_t*)g, (la_t*)&blds[(size_t)pp * 8], 16, 0, 0);
    }
    __syncthreads();

#pragma unroll
    for (int si = 0; si < 2; si++) {
        const int r0 = rowbase + wv * 128 + si * 64;

        // A fragments: rows r0 + rs*16 + l15, k = kk*32 + quad*8 + [0..7]
        short8 af[4][2];
#pragma unroll
        for (int rs = 0; rs < 4; rs++)
#pragma unroll
            for (int kk = 0; kk < 2; kk++)
                af[rs][kk] = *(const short8*)(
                    Au + (size_t)(r0 + rs * 16 + l15) * DIM + kk * 32 + quad * 8);

        float rowsum[4][4];
#pragma unroll
        for (int rs = 0; rs < 4; rs++)
#pragma unroll
            for (int r = 0; r < 4; r++) rowsum[rs][r] = 0.0f;

#pragma unroll 4
        for (int ct = 0; ct < BCOLS / 16; ct++) {
            const int jl = ct * 16 + l15;
            const int sw = l15 & 7;     // == jl & 7
            const short8 b0 = *(const short8*)&blds[(size_t)(jl * 8 + (quad ^ sw)) * 8];
            const short8 b1 = *(const short8*)&blds[(size_t)(jl * 8 + ((4 + quad) ^ sw)) * 8];
#pragma unroll
            for (int rs = 0; rs < 4; rs++) {
                f32x4 acc = {0.f, 0.f, 0.f, 0.f};
                acc = __builtin_amdgcn_mfma_f32_16x16x32_bf16(af[rs][0], b0, acc, 0, 0, 0);
                acc = __builtin_amdgcn_mfma_f32_16x16x32_bf16(af[rs][1], b1, acc, 0, 0, 0);
#pragma unroll
                for (int r = 0; r < 4; r++)
                    rowsum[rs][r] += __builtin_amdgcn_exp2f(acc[r]);
            }
        }

        // Sum over the 16 columns held by each l15-group.
#pragma unroll
        for (int m = 1; m < 16; m <<= 1)
#pragma unroll
            for (int rs = 0; rs < 4; rs++)
#pragma unroll
                for (int r = 0; r < 4; r++)
                    rowsum[rs][r] += __shfl_xor(rowsum[rs][r], m, 64);

        if (l15 == 0) {
#pragma unroll
            for (int rs = 0; rs < 4; rs++)
#pragma unroll
                for (int r = 0; r < 4; r++)
                    atomicAdd(&total[r0 + rs * 16 + quad * 4 + r], rowsum[rs][r]);
        }
    }

    // Last block finalizes (device-scope fences; pattern verified R5/R6).
    __shared__ int lastflag;
    __syncthreads();
    if (tid == 0) {
        __threadfence();
        lastflag = (atomicAdd(ticket, 1) == NBLK - 1);
    }
    __syncthreads();
    if (lastflag) {
        __threadfence();
        __shared__ float red[8];
        float s = 0.0f;
#pragma unroll
        for (int k = 0; k < NROWS / 512; k++) {
            const int idx = k * 512 + tid;
            s += __log2f(total[idx] + EPS) * LN2F - p[idx];
        }
#pragma unroll
        for (int m = 1; m < 64; m <<= 1) s += __shfl_xor(s, m, 64);
        if ((tid & 63) == 0) red[tid >> 6] = s;
        __syncthreads();
        if (tid == 0) {
            float t = 0.0f;
#pragma unroll
            for (int k = 0; k < 8; k++) t += red[k];
            out[0] = t * (1.0f / (float)NROWS);
        }
    }
}

extern "C" void kernel_launch(void* const* d_in, const int* in_sizes, int n_in,
                              void* d_out, int out_size, void* d_ws, size_t ws_size,
                              hipStream_t stream) {
    const float* u = (const float*)d_in[0];
    const float* v = (const float*)d_in[1];

    char* ws = (char*)d_ws;
    __hip_bfloat16* a = (__hip_bfloat16*)(ws);                                  // 2 MB
    __hip_bfloat16* w = (__hip_bfloat16*)(ws + (size_t)NROWS * DIM * 2);        // 2 MB
    float* p    = (float*)(ws + (size_t)NROWS * DIM * 4);                       // 64 KB
    float* tot  = (float*)(ws + (size_t)NROWS * DIM * 4 + (size_t)NROWS * 4);   // 64 KB
    int*   tick = (int*)  (ws + (size_t)NROWS * DIM * 4 + (size_t)NROWS * 8);   // 4 B

    prep_kernel<<<NROWS / 4, 256, 0, stream>>>(u, v, a, w, p, tot, tick);
    score_kernel<<<NBLK, 512, 0, stream>>>(a, w, tot, p, tick, (float*)d_out);
}

// Round 8
// 111.198 us; speedup vs baseline: 1.1411x; 1.1411x over previous
//
#include <hip/hip_runtime.h>
#include <hip/hip_bf16.h>

#define NROWS 16384
#define DIM 64
#define BCOLS 512                  // B tile: 512 cols x 64 k = 64 KB, staged ONCE
#define BROWS 1024                 // 8 waves x 2 si x 64 rows
#define NCS (NROWS / BCOLS)        // 32
#define NRG (NROWS / BROWS)        // 16
#define NBLK (NRG * NCS)           // 512 = exactly 2 blocks/CU (64 KB LDS each)

static constexpr float TAU = 0.28f;
static constexpr float EPS = 1e-8f;
static constexpr float EXP2_SCALE = (float)(1.0 / (0.28 * 0.6931471805599453));
static constexpr float LN2F = 0.69314718055994530942f;

using short8 = __attribute__((ext_vector_type(8))) short;
using f32x4  = __attribute__((ext_vector_type(4))) float;

typedef __attribute__((address_space(1))) const unsigned char ga_t;
typedef __attribute__((address_space(3))) unsigned char la_t;

// Kernel 1: per-row L2 normalize; A = bf16(EXP2_SCALE*u_norm),
// W = bf16(u_norm+i_norm), p[n] = dot/TAU; zero total[] and the ticket.
__global__ __launch_bounds__(256) void prep_kernel(
    const float* __restrict__ u, const float* __restrict__ v,
    __hip_bfloat16* __restrict__ a_out, __hip_bfloat16* __restrict__ w_out,
    float* __restrict__ p_out, float* __restrict__ total, int* __restrict__ ticket)
{
    const int lane = threadIdx.x & 63;
    const int wv   = threadIdx.x >> 6;
    const int row  = blockIdx.x * 4 + wv;

    const float uu = u[row * DIM + lane];
    const float ii = v[row * DIM + lane];
    float su = uu * uu, si = ii * ii, sd = uu * ii;
#pragma unroll
    for (int m = 1; m < 64; m <<= 1) {
        su += __shfl_xor(su, m, 64);
        si += __shfl_xor(si, m, 64);
        sd += __shfl_xor(sd, m, 64);
    }
    const float inv_u = 1.0f / fmaxf(sqrtf(su), 1e-12f);
    const float inv_i = 1.0f / fmaxf(sqrtf(si), 1e-12f);
    const float un = uu * inv_u;
    const float in = ii * inv_i;
    a_out[row * DIM + lane] = __float2bfloat16(EXP2_SCALE * un);
    w_out[row * DIM + lane] = __float2bfloat16(un + in);
    if (lane == 0) {
        p_out[row] = sd * inv_u * inv_i * (1.0f / TAU);
        total[row] = 0.0f;
    }
    if (blockIdx.x == 0 && threadIdx.x == 0) ticket[0] = 0;
}

// Kernel 2: fused GEMM + exp + row-sum (+ last-block finalize).
// R4's measured-best shape (512 thr, 64 KB tile staged ONCE, one barrier,
// 512 blocks = exactly 2/CU) with R7's rs=4 inner loop: each LDS B-pair
// feeds 8 MFMAs (halves LDS read traffic vs R4) and si count drops 4->2
// (halves si-boundary stalls and atomic count). VGPR for this inner loop
// measured 44 in R7 -- well under the 128 cap, no spill risk.
__global__ __launch_bounds__(512, 4) void score_kernel(
    const __hip_bfloat16* __restrict__ A, const __hip_bfloat16* __restrict__ W,
    float* __restrict__ total, const float* __restrict__ p,
    int* __restrict__ ticket, float* __restrict__ out)
{
    __shared__ alignas(16) ushort blds[BCOLS * DIM];   // 64 KB

    const int tid  = threadIdx.x;
    const int lane = tid & 63;
    const int wv   = tid >> 6;          // 0..7
    const int l15  = lane & 15;
    const int quad = lane >> 4;
    const int cs   = blockIdx.x & (NCS - 1);
    const int rg   = blockIdx.x >> 5;
    const int col0    = cs * BCOLS;
    const int rowbase = rg * BROWS;

    const ushort* Au = (const ushort*)A;
    const ushort* Wu = (const ushort*)W;

    // Stage B ONCE: 4096 16-B chunks, 8/thread; physical slot pp -> LDS
    // pp*16, global k-chunk c = (pp&7) ^ (col&7) (read-side swizzle
    // cancels it; 0 bank conflicts measured R4-R7).
#pragma unroll
    for (int q = 0; q < 8; q++) {
        const int pp = q * 512 + tid;
        const int j  = pp >> 3;
        const int c  = (pp & 7) ^ (j & 7);
        const ushort* g = Wu + (size_t)(col0 + j) * DIM + c * 8;
        __builtin_amdgcn_global_load_lds((ga_t*)g, (la_t*)&blds[(size_t)pp * 8], 16, 0, 0);
    }
    __syncthreads();

#pragma unroll
    for (int si = 0; si < 2; si++) {
        const int r0 = rowbase + wv * 128 + si * 64;

        // A fragments: rows r0 + rs*16 + l15, k = kk*32 + quad*8 + [0..7]
        short8 af[4][2];
#pragma unroll
        for (int rs = 0; rs < 4; rs++)
#pragma unroll
            for (int kk = 0; kk < 2; kk++)
                af[rs][kk] = *(const short8*)(
                    Au + (size_t)(r0 + rs * 16 + l15) * DIM + kk * 32 + quad * 8);

        float rowsum[4][4];
#pragma unroll
        for (int rs = 0; rs < 4; rs++)
#pragma unroll
            for (int r = 0; r < 4; r++) rowsum[rs][r] = 0.0f;

#pragma unroll 4
        for (int ct = 0; ct < BCOLS / 16; ct++) {
            const int jl = ct * 16 + l15;
            const int sw = l15 & 7;     // == jl & 7
            const short8 b0 = *(const short8*)&blds[(size_t)(jl * 8 + (quad ^ sw)) * 8];
            const short8 b1 = *(const short8*)&blds[(size_t)(jl * 8 + ((4 + quad) ^ sw)) * 8];
#pragma unroll
            for (int rs = 0; rs < 4; rs++) {
                f32x4 acc = {0.f, 0.f, 0.f, 0.f};
                acc = __builtin_amdgcn_mfma_f32_16x16x32_bf16(af[rs][0], b0, acc, 0, 0, 0);
                acc = __builtin_amdgcn_mfma_f32_16x16x32_bf16(af[rs][1], b1, acc, 0, 0, 0);
#pragma unroll
                for (int r = 0; r < 4; r++)
                    rowsum[rs][r] += __builtin_amdgcn_exp2f(acc[r]);
            }
        }

        // Sum over the 16 columns held by each l15-group.
#pragma unroll
        for (int m = 1; m < 16; m <<= 1)
#pragma unroll
            for (int rs = 0; rs < 4; rs++)
#pragma unroll
                for (int r = 0; r < 4; r++)
                    rowsum[rs][r] += __shfl_xor(rowsum[rs][r], m, 64);

        if (l15 == 0) {
#pragma unroll
            for (int rs = 0; rs < 4; rs++)
#pragma unroll
                for (int r = 0; r < 4; r++)
                    atomicAdd(&total[r0 + rs * 16 + quad * 4 + r], rowsum[rs][r]);
        }
    }

    // Last block finalizes (device-scope fences; pattern verified R5-R7).
    __shared__ int lastflag;
    __syncthreads();
    if (tid == 0) {
        __threadfence();
        lastflag = (atomicAdd(ticket, 1) == NBLK - 1);
    }
    __syncthreads();
    if (lastflag) {
        __threadfence();
        __shared__ float red[8];
        float s = 0.0f;
#pragma unroll
        for (int k = 0; k < NROWS / 512; k++) {
            const int idx = k * 512 + tid;
            s += __log2f(total[idx] + EPS) * LN2F - p[idx];
        }
#pragma unroll
        for (int m = 1; m < 64; m <<= 1) s += __shfl_xor(s, m, 64);
        if ((tid & 63) == 0) red[tid >> 6] = s;
        __syncthreads();
        if (tid == 0) {
            float t = 0.0f;
#pragma unroll
            for (int k = 0; k < 8; k++) t += red[k];
            out[0] = t * (1.0f / (float)NROWS);
        }
    }
}

extern "C" void kernel_launch(void* const* d_in, const int* in_sizes, int n_in,
                              void* d_out, int out_size, void* d_ws, size_t ws_size,
                              hipStream_t stream) {
    const float* u = (const float*)d_in[0];
    const float* v = (const float*)d_in[1];

    char* ws = (char*)d_ws;
    __hip_bfloat16* a = (__hip_bfloat16*)(ws);                                  // 2 MB
    __hip_bfloat16* w = (__hip_bfloat16*)(ws + (size_t)NROWS * DIM * 2);        // 2 MB
    float* p    = (float*)(ws + (size_t)NROWS * DIM * 4);                       // 64 KB
    float* tot  = (float*)(ws + (size_t)NROWS * DIM * 4 + (size_t)NROWS * 4);   // 64 KB
    int*   tick = (int*)  (ws + (size_t)NROWS * DIM * 4 + (size_t)NROWS * 8);   // 4 B

    prep_kernel<<<NROWS / 4, 256, 0, stream>>>(u, v, a, w, p, tot, tick);
    score_kernel<<<NBLK, 512, 0, stream>>>(a, w, tot, p, tick, (float*)d_out);
}